// Round 1
// baseline (170.587 us; speedup 1.0000x reference)
//
#include <hip/hip_runtime.h>
#include <hip/hip_bf16.h>

// BiPairwiseNegativeCELoss on MI355X.
// Inputs: q, d, nd : [16384, 128] fp32. Output: scalar fp32 loss.
// loss = 0.5 * ( mean(softplus(q.nd_row - q.d_row))
//              + mean(softplus(max_c(q_b . d_c, diag -1e6) - q_b.d_b)) )

#define BATCH 16384
#define DDIM  128
#define ROWS_PER_BLOCK 64       // 4 row-subtiles of 16 per wave
#define COLS_PER_WAVE  4096     // 16384 / 4 waves
#define CHUNK_COLS     32       // cols staged per LDS buffer
#define NCHUNKS        (COLS_PER_WAVE / CHUNK_COLS)   // 128

typedef __attribute__((ext_vector_type(8))) short bf16x8;   // 8 bf16 = 4 VGPRs
typedef __attribute__((ext_vector_type(4))) float f32x4;

__device__ __forceinline__ float softplus_f(float x) {
    // log(1+exp(x)), numerically stable
    return (x > 0.0f) ? x + log1pf(expf(-x)) : log1pf(expf(x));
}

__device__ __forceinline__ ushort f2bf_rne(float x) {
    unsigned u = __float_as_uint(x);
    unsigned r = (u + 0x7FFFu + ((u >> 16) & 1u)) >> 16;
    return (ushort)r;
}

// ---------------------------------------------------------------------------
// Kernel A: pairwise dots (fp32, exact), loss1 partial sums, and bf16 casts.
// grid 256 x 256 threads; each block owns 64 rows.
// ---------------------------------------------------------------------------
__global__ __launch_bounds__(256) void prep_kernel(
    const float* __restrict__ q, const float* __restrict__ d,
    const float* __restrict__ nd,
    ushort* __restrict__ qb, ushort* __restrict__ db,
    float* __restrict__ pos, float* __restrict__ acc)
{
    const int t   = threadIdx.x;
    const int blk = blockIdx.x;

    // --- pairwise dot products: 4 threads per row, 32 elems each ---
    const int r    = blk * 64 + (t >> 2);
    const int part = t & 3;
    const float4* q4 = (const float4*)(q + (size_t)r * DDIM + part * 32);
    const float4* d4 = (const float4*)(d + (size_t)r * DDIM + part * 32);
    const float4* n4 = (const float4*)(nd + (size_t)r * DDIM + part * 32);
    float ps = 0.0f, ns = 0.0f;
#pragma unroll
    for (int i = 0; i < 8; ++i) {
        float4 a = q4[i], b = d4[i], c = n4[i];
        ps += a.x * b.x + a.y * b.y + a.z * b.z + a.w * b.w;
        ns += a.x * c.x + a.y * c.y + a.z * c.z + a.w * c.w;
    }
    ps += __shfl_xor(ps, 1); ps += __shfl_xor(ps, 2);
    ns += __shfl_xor(ns, 1); ns += __shfl_xor(ns, 2);

    float contrib = 0.0f;
    if (part == 0) {
        pos[r] = ps;                       // == scores[b][b], exact fp32
        contrib = softplus_f(ns - ps);     // loss1 per-row term
    }

    __shared__ float red[256];
    red[t] = contrib;
    __syncthreads();
#pragma unroll
    for (int s = 128; s > 0; s >>= 1) {
        if (t < s) red[t] += red[t + s];
        __syncthreads();
    }
    if (t == 0) atomicAdd(acc, red[0]);

    // --- cast q, d to bf16 (RNE), fully coalesced float4 -> ushort4 ---
    const size_t base = (size_t)blk * (ROWS_PER_BLOCK * DDIM);
#pragma unroll
    for (int i = 0; i < 8; ++i) {
        size_t idx = base + (size_t)i * 1024 + (size_t)t * 4;
        float4 v = *(const float4*)(q + idx);
        ushort4 o;
        o.x = f2bf_rne(v.x); o.y = f2bf_rne(v.y);
        o.z = f2bf_rne(v.z); o.w = f2bf_rne(v.w);
        *(ushort4*)(qb + idx) = o;
        float4 u = *(const float4*)(d + idx);
        ushort4 p;
        p.x = f2bf_rne(u.x); p.y = f2bf_rne(u.y);
        p.z = f2bf_rne(u.z); p.w = f2bf_rne(u.w);
        *(ushort4*)(db + idx) = p;
    }
}

// ---------------------------------------------------------------------------
// Async stage of a 32-col x 128-k bf16 chunk into LDS with XOR-swizzled
// 16B k-segments (swizzle applied via the per-lane GLOBAL address, since the
// LDS destination of global_load_lds is fixed at base + lane*16).
// LDS layout: col-major rows of 256B; segment s of col c lives at
//   c*256 + (s ^ (c&15))*16.
// ---------------------------------------------------------------------------
__device__ __forceinline__ void stage32(const ushort* __restrict__ db,
                                        ushort* lbuf, int colBase, int l)
{
#pragma unroll
    for (int i = 0; i < 8; ++i) {
        int c_local = i * 4 + (l >> 4);                 // 0..31
        int kseg    = (l & 15) ^ (c_local & 15);        // global 16B segment
        const ushort* g = db + (size_t)(colBase + c_local) * DDIM + kseg * 8;
        __builtin_amdgcn_global_load_lds(
            (const __attribute__((address_space(1))) void*)g,
            (__attribute__((address_space(3))) void*)(lbuf + i * 512),
            16, 0, 0);
    }
}

// ---------------------------------------------------------------------------
// Kernel B: fused GEMM + row-max. 256 blocks x 256 threads (1 block/CU).
// Block owns 64 rows (A-frags in registers, whole K=128). The 4 waves split
// columns 4-way; each wave double-buffers its own 32-col LDS chunks with
// explicit vmcnt waits -- no __syncthreads in the main loop.
// ---------------------------------------------------------------------------
__global__ __launch_bounds__(256, 1) void inbatch_kernel(
    const ushort* __restrict__ qb, const ushort* __restrict__ db,
    const float* __restrict__ pos, float* __restrict__ acc)
{
    __shared__ ushort stg[4][2][CHUNK_COLS * DDIM];   // 4 waves x dbuf x 8KB = 64KB

    const int t      = threadIdx.x;
    const int w      = t >> 6;
    const int l      = t & 63;
    const int lane16 = l & 15;
    const int quad   = l >> 4;
    const int row0   = blockIdx.x * ROWS_PER_BLOCK;

    // A fragments: lane l holds Q[row0 + rs*16 + (l&15)][ks*32 + quad*8 + j]
    bf16x8 afrag[4][4];
#pragma unroll
    for (int rs = 0; rs < 4; ++rs)
#pragma unroll
        for (int ks = 0; ks < 4; ++ks)
            afrag[rs][ks] = *(const bf16x8*)(
                qb + (size_t)(row0 + rs * 16 + lane16) * DDIM + ks * 32 + quad * 8);

    float runmax[4][4];
#pragma unroll
    for (int rs = 0; rs < 4; ++rs)
#pragma unroll
        for (int r = 0; r < 4; ++r) runmax[rs][r] = -3.0e38f;

    const int colW = w * COLS_PER_WAVE;
    ushort* buf0 = &stg[w][0][0];
    ushort* buf1 = &stg[w][1][0];

    stage32(db, buf0, colW, l);   // prologue: chunk 0

    for (int ch = 0; ch < NCHUNKS; ++ch) {
        ushort* cur = (ch & 1) ? buf1 : buf0;
        ushort* nxt = (ch & 1) ? buf0 : buf1;
        if (ch + 1 < NCHUNKS) {
            stage32(db, nxt, colW + (ch + 1) * CHUNK_COLS, l);
            // 16 outstanding global_load_lds; wait until only the 8 newest
            // remain => current buffer complete.  vmcnt(8), lgkm/exp untouched.
            __builtin_amdgcn_s_waitcnt(8 | (7 << 4) | (15 << 8));
        } else {
            __builtin_amdgcn_s_waitcnt(0 | (7 << 4) | (15 << 8));  // vmcnt(0)
        }
        asm volatile("" ::: "memory");   // don't hoist ds_reads above the wait

        // B fragments: lane l holds D[c0 + (l&15)][ks*32 + quad*8 + j]
        bf16x8 bfrag[2][4];
#pragma unroll
        for (int ct = 0; ct < 2; ++ct)
#pragma unroll
            for (int ks = 0; ks < 4; ++ks) {
                int c_local = ct * 16 + lane16;
                int kseg    = ks * 4 + quad;
                bfrag[ct][ks] = *(const bf16x8*)(
                    cur + c_local * DDIM + ((kseg ^ lane16) * 8));
            }

        const int colBase = colW + ch * CHUNK_COLS;
#pragma unroll
        for (int rs = 0; rs < 4; ++rs) {
#pragma unroll
            for (int ct = 0; ct < 2; ++ct) {
                f32x4 s = {0.0f, 0.0f, 0.0f, 0.0f};
#pragma unroll
                for (int ks = 0; ks < 4; ++ks)
                    s = __builtin_amdgcn_mfma_f32_16x16x32_bf16(
                        afrag[rs][ks], bfrag[ct][ks], s, 0, 0, 0);
                const int cg0 = colBase + ct * 16;
                const int rg0 = row0 + rs * 16;
                if (cg0 == rg0) {              // diagonal tile: scores - 1e6
#pragma unroll
                    for (int r = 0; r < 4; ++r)
                        if (quad * 4 + r == lane16) s[r] -= 1.0e6f;
                }
#pragma unroll
                for (int r = 0; r < 4; ++r)
                    runmax[rs][r] = fmaxf(runmax[rs][r], s[r]);
            }
        }
    }

    // reduce max across the 16 lanes of each quad-group (same row, cols mod 16)
#pragma unroll
    for (int rs = 0; rs < 4; ++rs)
#pragma unroll
        for (int r = 0; r < 4; ++r) {
            float m = runmax[rs][r];
            m = fmaxf(m, __shfl_xor(m, 1));
            m = fmaxf(m, __shfl_xor(m, 2));
            m = fmaxf(m, __shfl_xor(m, 4));
            m = fmaxf(m, __shfl_xor(m, 8));
            runmax[rs][r] = m;
        }

    __syncthreads();                       // staging buffers now reusable
    float* smax = (float*)&stg[0][0][0];   // [4 waves][64 rows]
    if (lane16 == 0) {
#pragma unroll
        for (int rs = 0; rs < 4; ++rs)
#pragma unroll
            for (int r = 0; r < 4; ++r)
                smax[w * 64 + rs * 16 + quad * 4 + r] = runmax[rs][r];
    }
    __syncthreads();

    if (t < 64) {   // wave 0: combine 4 col-ranges, softplus, block sum
        float fm = fmaxf(fmaxf(smax[t], smax[64 + t]),
                         fmaxf(smax[128 + t], smax[192 + t]));
        float c = softplus_f(fm - pos[row0 + t]);
        c += __shfl_xor(c, 1);  c += __shfl_xor(c, 2);
        c += __shfl_xor(c, 4);  c += __shfl_xor(c, 8);
        c += __shfl_xor(c, 16); c += __shfl_xor(c, 32);
        if (t == 0) atomicAdd(acc + 1, c);
    }
}

__global__ void finalize_kernel(const float* __restrict__ acc,
                                float* __restrict__ out)
{
    out[0] = (acc[0] + acc[1]) * (1.0f / (2.0f * BATCH));
}

extern "C" void kernel_launch(void* const* d_in, const int* in_sizes, int n_in,
                              void* d_out, int out_size, void* d_ws, size_t ws_size,
                              hipStream_t stream)
{
    const float* q  = (const float*)d_in[0];
    const float* d  = (const float*)d_in[1];
    const float* nd = (const float*)d_in[2];
    float* out = (float*)d_out;

    char* ws   = (char*)d_ws;
    float*  acc = (float*)ws;                          // 2 floats
    float*  pos = (float*)(ws + 256);                  // 16384 floats = 64KB
    ushort* qb  = (ushort*)(ws + 256 + 65536);         // 4MB bf16
    ushort* db  = (ushort*)(ws + 256 + 65536 + 4194304); // 4MB bf16

    hipMemsetAsync(acc, 0, 8, stream);
    prep_kernel<<<BATCH / 64, 256, 0, stream>>>(q, d, nd, qb, db, pos, acc);
    inbatch_kernel<<<BATCH / ROWS_PER_BLOCK, 256, 0, stream>>>(qb, db, pos, acc);
    finalize_kernel<<<1, 1, 0, stream>>>(acc, out);
}